// Round 6
// baseline (321.440 us; speedup 1.0000x reference)
//
#include <hip/hip_runtime.h>

typedef __attribute__((ext_vector_type(8))) short bhalf8;
typedef __attribute__((ext_vector_type(4))) float f32x4;

__device__ __forceinline__ ushort f2bf(float f) {
  unsigned u = __builtin_bit_cast(unsigned, f);
  unsigned r = u + 0x7fffu + ((u >> 16) & 1u);
  return (ushort)(r >> 16);
}

// async global->LDS, 16B per lane. Dest = wave-uniform base + lane*16.
__device__ __forceinline__ void gld16(const ushort* g, ushort* l) {
  __builtin_amdgcn_global_load_lds((const __attribute__((address_space(1))) void*)g,
                                   (__attribute__((address_space(3))) void*)l, 16, 0, 0);
}

// ---------------- prep: converts, transposes, mask bitpack, cvec ------------
__global__ __launch_bounds__(256) void prep_kernel(
    const float* __restrict__ q, const int* __restrict__ mask,
    const float* __restrict__ eps1, const float* __restrict__ U_w,
    const float* __restrict__ V_w, const float* __restrict__ Wq,
    const float* __restrict__ Wk, const float* __restrict__ Wv,
    const float* __restrict__ Wo, const float* __restrict__ U_b,
    const float* __restrict__ V_b,
    ushort* __restrict__ qb, unsigned long long* __restrict__ mbits,
    ushort* __restrict__ uwb, ushort* __restrict__ vwb,
    ushort* __restrict__ e1b, ushort* __restrict__ e1t,
    ushort* __restrict__ wqkv, ushort* __restrict__ wot,
    float* __restrict__ cvec) {
  int i = blockIdx.x * 256 + threadIdx.x;
  if (i < 4194304) {
    qb[i] = f2bf(q[i]);
  } else if (i < 12582912) {
    int j = i - 4194304;  // (b,qq,g) flat
    unsigned long long bb = __ballot(mask[j] != 0);
    if ((threadIdx.x & 63) == 0) {
      int b = j >> 20, qq = (j >> 10) & 1023, g = j & 1023;
      mbits[((size_t)b * 16 + (g >> 6)) * 1024 + qq] = bb;
    }
  } else if (i < 13369344) {
    int j = i - 12582912;
    uwb[j] = f2bf(U_w[j]);
  } else if (i < 14155776) {
    int j = i - 13369344;
    vwb[j] = f2bf(V_w[j]);
  } else if (i < 14417920) {
    int j = i - 14155776;
    e1b[j] = f2bf(eps1[j]);
  } else if (i < 14680064) {
    int j = i - 14417920; int n = j >> 9, k = j & 511;
    e1t[j] = f2bf(eps1[k * 512 + n]);
  } else if (i < 15466496) {
    int j = i - 14680064; int n = j >> 9, d = j & 511;
    const float* W = (n < 512) ? Wq : (n < 1024 ? Wk : Wv);
    float sc = (n < 512) ? 0.02255252509f : 1.0f;  // (1/64)*log2(e) into Wq
    int nl = n & 511;
    wqkv[j] = f2bf(W[((nl >> 6) * 512 + d) * 64 + (nl & 63)] * sc);
  } else if (i < 15728640) {
    int j = i - 15466496; int d = j >> 9, hv = j & 511;
    wot[j] = f2bf(Wo[hv * 512 + d]);
  } else {
    int j = i - 15728640;  // cvec: 98304 threads = 1536 waves
    int idx = j >> 6, ln = j & 63;
    int l = idx >> 9;
    const float* vr = V_w + (size_t)idx * 512 + ln * 8;
    const float* ur = U_b + l * 512 + ln * 8;
    float s = 0;
#pragma unroll
    for (int t = 0; t < 8; t++) s += vr[t] * ur[t];
#pragma unroll
    for (int off = 1; off < 64; off <<= 1) s += __shfl_xor(s, off, 64);
    if (ln == 0) cvec[idx] = s + V_b[idx];
  }
}

// ---------------- mask transpose: mbits[b][gw][q] -> mT2[b][qw][g] inverted -
__global__ __launch_bounds__(256) void mrepack_kernel(
    const unsigned long long* __restrict__ mbits,
    unsigned long long* __restrict__ mT2) {
  int id = blockIdx.x * 4 + (threadIdx.x >> 6);  // (b,gw,qw) 8*16*16
  int lane = threadIdx.x & 63;
  int b = id >> 8, gw = (id >> 4) & 15, qw = id & 15;
  unsigned long long row = mbits[((size_t)b * 16 + gw) * 1024 + qw * 64 + lane];
  unsigned long long keep = 0;
  for (int j = 0; j < 64; j++) {
    unsigned long long bal = __ballot((row >> j) & 1ull);
    if (lane == j) keep = bal;
  }
  mT2[((size_t)b * 16 + qw) * 1024 + gw * 64 + lane] = ~keep;
}

// ---------------- bf16 MFMA GEMM, NT, BK=64, pipelined gld16 ----------------
// C[M,N] = A[M,K]*Bt[N,K]^T, tile 128 x BN, 256 thr. Output region reg=n0>>9:
// reg==ktreg -> K-tiled scatter KtT[bh][g/16][d/32][g%16][d%32]
// reg==vtreg -> V-tiled scatter VtT[bh][g/16][v][g%16]
// else Freg fp32 or Oreg bf16 row-major (+bias).
template <int BN>
__global__ __launch_bounds__(256) void gemm_nt(
    const ushort* __restrict__ A0, const ushort* __restrict__ A1,
    const ushort* __restrict__ Bt0, const ushort* __restrict__ Bt1,
    int bsplit, int mstride, int M, int K,
    ushort* __restrict__ O0, const float* __restrict__ b0,
    ushort* __restrict__ O1, const float* __restrict__ b1,
    ushort* __restrict__ O2, const float* __restrict__ b2,
    float* __restrict__ F0, float* __restrict__ F1,
    int ktreg, int vtreg) {
  __shared__ ushort As[128 * 64];
  __shared__ ushort Bs[BN * 64];
  int tid = threadIdx.x;
  int wave = tid >> 6, lane = tid & 63;
  int quad = lane >> 4, col = lane & 15;
  int m0 = blockIdx.x * 128, n0 = blockIdx.y * BN;
  const ushort* A = (A1 && n0 >= 512) ? A1 : A0;
  const ushort* Bp = ((n0 < bsplit) ? Bt0 + (size_t)n0 * K
                                    : Bt1 + (size_t)(n0 - bsplit) * K) +
                     (size_t)(m0 >> 9) * mstride;
  constexpr int NI = BN / 32;
  int wm = (BN == 128) ? (wave >> 1) * 64 : (wave & 1) * 64;
  int wn = (BN == 128) ? (wave & 1) * 64 : (wave >> 1) * 32;
  f32x4 acc[4][NI] = {};
  int srow = wave * 16 + (lane >> 3);  // 8 rows per gld16
  int skc = (lane & 7) * 8;
  const ushort* gA = A + (size_t)(m0 + srow) * K + skc;
  const ushort* gB = Bp + (size_t)srow * K + skc;
  ushort* lA = &As[(wave * 16) * 64];
  ushort* lB = &Bs[(wave * 16) * 64];
  const size_t rK8 = (size_t)8 * K, rK64 = (size_t)64 * K;

  // stage tile 0
  gld16(gA, lA);
  gld16(gA + rK8, lA + 8 * 64);
  gld16(gA + rK64, lA + 64 * 64);
  gld16(gA + rK64 + rK8, lA + 72 * 64);
  gld16(gB, lB);
  gld16(gB + rK8, lB + 8 * 64);
  if (BN == 128) {
    gld16(gB + rK64, lB + 64 * 64);
    gld16(gB + rK64 + rK8, lB + 72 * 64);
  }

  for (int k0 = 0; k0 < K; k0 += 64) {
    __syncthreads();  // vmcnt drained: tile staged; prev readers done
    bhalf8 af[4], bg[NI];
#pragma unroll
    for (int i = 0; i < 4; i++)
      af[i] = *(bhalf8*)&As[(wm + i * 16 + col) * 64 + quad * 8];
#pragma unroll
    for (int i = 0; i < NI; i++)
      bg[i] = *(bhalf8*)&Bs[(wn + i * 16 + col) * 64 + quad * 8];
#pragma unroll
    for (int mi = 0; mi < 4; mi++)
#pragma unroll
      for (int ni = 0; ni < NI; ni++)
        acc[mi][ni] = __builtin_amdgcn_mfma_f32_16x16x32_bf16(af[mi], bg[ni], acc[mi][ni], 0, 0, 0);
    bhalf8 af2[4], bg2[NI];
#pragma unroll
    for (int i = 0; i < 4; i++)
      af2[i] = *(bhalf8*)&As[(wm + i * 16 + col) * 64 + 32 + quad * 8];
#pragma unroll
    for (int i = 0; i < NI; i++)
      bg2[i] = *(bhalf8*)&Bs[(wn + i * 16 + col) * 64 + 32 + quad * 8];
    __syncthreads();  // all waves done reading; LDS free
    if (k0 + 64 < K) {  // stage next tile; overlaps second MFMA half
      const ushort* a = gA + k0 + 64;
      const ushort* b = gB + k0 + 64;
      gld16(a, lA);
      gld16(a + rK8, lA + 8 * 64);
      gld16(a + rK64, lA + 64 * 64);
      gld16(a + rK64 + rK8, lA + 72 * 64);
      gld16(b, lB);
      gld16(b + rK8, lB + 8 * 64);
      if (BN == 128) {
        gld16(b + rK64, lB + 64 * 64);
        gld16(b + rK64 + rK8, lB + 72 * 64);
      }
    }
#pragma unroll
    for (int mi = 0; mi < 4; mi++)
#pragma unroll
      for (int ni = 0; ni < NI; ni++)
        acc[mi][ni] = __builtin_amdgcn_mfma_f32_16x16x32_bf16(af2[mi], bg2[ni], acc[mi][ni], 0, 0, 0);
  }

  int reg = n0 >> 9;
  ushort* Oreg = (reg == 0) ? O0 : (reg == 1 ? O1 : O2);
  const float* breg = (reg == 0) ? b0 : (reg == 1 ? b1 : b2);
  float* Freg = (reg == 0) ? F0 : (reg == 1 ? F1 : nullptr);
#pragma unroll
  for (int mi = 0; mi < 4; mi++)
#pragma unroll
    for (int ni = 0; ni < NI; ni++) {
      int cn = n0 + wn + ni * 16 + col;
      int cnl = cn & 511;
      int cmb = m0 + wm + mi * 16 + quad * 4;
      float bvv = breg ? breg[cnl] : 0.f;
      if (reg == vtreg) {
        int bhh = (cmb >> 10) * 8 + (cnl >> 6);
        size_t base = ((size_t)bhh * 64 + ((cmb & 1023) >> 4)) * 1024 +
                      (size_t)(cnl & 63) * 16 + (cmb & 15);
        ushort4 pk;
        pk.x = f2bf(acc[mi][ni][0] + bvv);
        pk.y = f2bf(acc[mi][ni][1] + bvv);
        pk.z = f2bf(acc[mi][ni][2] + bvv);
        pk.w = f2bf(acc[mi][ni][3] + bvv);
        *(ushort4*)&Oreg[base] = pk;
      } else if (reg == ktreg) {
        int bhh = (cmb >> 10) * 8 + (cnl >> 6);
        size_t base = ((size_t)bhh * 64 + ((cmb & 1023) >> 4)) * 1024 +
                      (size_t)((cnl >> 5) & 1) * 512 + (size_t)(cmb & 15) * 32 + (cnl & 31);
#pragma unroll
        for (int r = 0; r < 4; r++)
          Oreg[base + r * 32] = f2bf(acc[mi][ni][r] + bvv);
      } else if (Freg) {
#pragma unroll
        for (int r = 0; r < 4; r++)
          Freg[(size_t)(cmb + r) * 512 + cnl] = acc[mi][ni][r] + bvv;
      } else {
#pragma unroll
        for (int r = 0; r < 4; r++)
          Oreg[(size_t)(cmb + r) * 512 + cnl] = f2bf(acc[mi][ni][r] + bvv);
      }
    }
}

// ---------------- fused LayerNorm + ReLU + residual (z fp32, t bf16) --------
__global__ __launch_bounds__(256) void ln_kernel(
    const float* __restrict__ z, const ushort* __restrict__ tb,
    const float* __restrict__ lgam, const float* __restrict__ lbet,
    ushort* __restrict__ hb) {
  int row = blockIdx.x * 4 + (threadIdx.x >> 6);
  int lane = threadIdx.x & 63;
  int cbase = lane * 8;
  const float* zr = z + (size_t)row * 512 + cbase;
  float x[8];
  *(float4*)&x[0] = *(const float4*)zr;
  *(float4*)&x[4] = *(const float4*)(zr + 4);
  float sum = 0;
#pragma unroll
  for (int i = 0; i < 8; i++) sum += x[i];
#pragma unroll
  for (int off = 1; off < 64; off <<= 1) sum += __shfl_xor(sum, off, 64);
  float mu = sum * (1.f / 512.f);
  float vs = 0;
#pragma unroll
  for (int i = 0; i < 8; i++) { float d = x[i] - mu; vs += d * d; }
#pragma unroll
  for (int off = 1; off < 64; off <<= 1) vs += __shfl_xor(vs, off, 64);
  float rstd = rsqrtf(vs * (1.f / 512.f) + 1e-5f);
  uint4 tr = *(const uint4*)&tb[(size_t)row * 512 + cbase];
  float tv[8];
  {
    const unsigned* u = (const unsigned*)&tr;
#pragma unroll
    for (int w = 0; w < 4; w++) {
      tv[2 * w] = __builtin_bit_cast(float, u[w] << 16);
      tv[2 * w + 1] = __builtin_bit_cast(float, u[w] & 0xFFFF0000u);
    }
  }
  ushort outv[8];
#pragma unroll
  for (int i = 0; i < 8; i++) {
    float val = (x[i] - mu) * rstd * lgam[cbase + i] + lbet[cbase + i];
    outv[i] = f2bf(tv[i] + fmaxf(val, 0.f));
  }
  *(uint4*)&hb[(size_t)row * 512 + cbase] = *(uint4*)outv;
}

// ---------------- flash attention, wave-g-split, tiled K/V loads ------------
// grid (64 bh, 16 qt), 4 waves, barrier-free main loop. K from
// KtT[bh][g/16][d/32][g%16][d%32] (per-instr 1KB contiguous), V from
// VtT[bh][g/16][v][g%16] (2x512B), mask from mT2[b][qw][g] pre-inverted
// (128B contiguous). Row sums via ones-column (5th PV MFMA).
__global__ __launch_bounds__(256, 2) void attn_kernel(
    const ushort* __restrict__ Qp, const ushort* __restrict__ KtT,
    const ushort* __restrict__ VtT, const unsigned long long* __restrict__ mT2,
    ushort* __restrict__ Op) {
  int bh = blockIdx.x, qt = blockIdx.y;
  int b = bh >> 3, h = bh & 7;
  __shared__ __align__(16) char pool[21504];  // Ps 4*5120B | reduce 64*84*4B
  int tid = threadIdx.x, wave = tid >> 6, lane = tid & 63;
  int quad = lane >> 4, col = lane & 15;
  int q0 = qt * 64;
  ushort* Ps = (ushort*)pool + wave * 2560;  // ushort units -> 5120 B/wave

  bhalf8 aq[4][2];
  {
    const ushort* qbase = &Qp[(size_t)(b * 1024 + q0 + col) * 512 + h * 64 + quad * 8];
#pragma unroll
    for (int qs = 0; qs < 4; qs++) {
      aq[qs][0] = *(const bhalf8*)(qbase + (size_t)(qs * 16) * 512);
      aq[qs][1] = *(const bhalf8*)(qbase + (size_t)(qs * 16) * 512 + 32);
    }
  }
  bhalf8 ones;
  {
    short v = (col == 0) ? (short)0x3F80 : (short)0;
#pragma unroll
    for (int j = 0; j < 8; j++) ones[j] = v;
  }
  f32x4 o[4][5] = {};
  const ushort* kbase = KtT + (size_t)bh * 65536 + wave * 1024 + col * 32 + quad * 8;
  const ushort* vbase = VtT + (size_t)bh * 65536 + wave * 1024 + (quad >> 1) * 4096 +
                        col * 16 + (quad & 1) * 8;
  const unsigned long long* mbase = &mT2[((size_t)b * 16 + qt) * 1024 + wave * 16 + col];

  for (int g0 = 0; g0 < 1024; g0 += 128) {
    int goff = g0 * 64;  // (g0>>4)*1024
    bhalf8 bk[2][2];
    bk[0][0] = *(const bhalf8*)(kbase + goff);
    bk[0][1] = *(const bhalf8*)(kbase + goff + 512);
    bk[1][0] = *(const bhalf8*)(kbase + goff + 4096);
    bk[1][1] = *(const bhalf8*)(kbase + goff + 4096 + 512);
    bhalf8 bv[4];
#pragma unroll
    for (int vs = 0; vs < 4; vs++)
      bv[vs] = *(const bhalf8*)(vbase + goff + vs * 256);
    unsigned long long i64_0 = mbase[g0] >> (quad * 4);
    unsigned long long i64_1 = mbase[g0 + 64] >> (quad * 4);
    unsigned i0lo = (unsigned)i64_0, i0hi = (unsigned)(i64_0 >> 32);
    unsigned i1lo = (unsigned)i64_1, i1hi = (unsigned)(i64_1 >> 32);
#pragma unroll
    for (int qs = 0; qs < 4; qs++) {
      f32x4 s0 = {}, s1 = {};
      s0 = __builtin_amdgcn_mfma_f32_16x16x32_bf16(aq[qs][0], bk[0][0], s0, 0, 0, 0);
      s0 = __builtin_amdgcn_mfma_f32_16x16x32_bf16(aq[qs][1], bk[0][1], s0, 0, 0, 0);
      s1 = __builtin_amdgcn_mfma_f32_16x16x32_bf16(aq[qs][0], bk[1][0], s1, 0, 0, 0);
      s1 = __builtin_amdgcn_mfma_f32_16x16x32_bf16(aq[qs][1], bk[1][1], s1, 0, 0, 0);
      unsigned w0 = (qs < 2) ? i0lo : i0hi;
      unsigned w1 = (qs < 2) ? i1lo : i1hi;
#pragma unroll
      for (int r = 0; r < 4; r++) {
        int pos = (qs & 1) * 16 + r;
        unsigned k0 = (unsigned)((int)(w0 << (31 - pos)) >> 31);  // all-ones if unmasked
        unsigned k1 = (unsigned)((int)(w1 << (31 - pos)) >> 31);
        unsigned p0 = __builtin_bit_cast(unsigned, __builtin_amdgcn_exp2f(s0[r])) & k0;
        unsigned p1 = __builtin_bit_cast(unsigned, __builtin_amdgcn_exp2f(s1[r])) & k1;
        Ps[(qs * 16 + quad * 4 + r) * 40 + col] = (ushort)((p0 + 0x8000u) >> 16);
        Ps[(qs * 16 + quad * 4 + r) * 40 + 16 + col] = (ushort)((p1 + 0x8000u) >> 16);
      }
    }
#pragma unroll
    for (int qs = 0; qs < 4; qs++) {
      bhalf8 ap = *(const bhalf8*)&Ps[(qs * 16 + col) * 40 + quad * 8];
#pragma unroll
      for (int vs = 0; vs < 4; vs++)
        o[qs][vs] = __builtin_amdgcn_mfma_f32_16x16x32_bf16(ap, bv[vs], o[qs][vs], 0, 0, 0);
      o[qs][4] = __builtin_amdgcn_mfma_f32_16x16x32_bf16(ap, ones, o[qs][4], 0, 0, 0);
    }
  }
  // cross-wave reduce of partial O (+l in slot 4)
  float* R = (float*)pool;
  for (int src = 1; src < 4; src++) {
    __syncthreads();
    if (wave == src) {
      float* dst = R + lane * 84;
#pragma unroll
      for (int qs = 0; qs < 4; qs++)
#pragma unroll
        for (int vs = 0; vs < 5; vs++)
          *(f32x4*)(dst + (qs * 5 + vs) * 4) = o[qs][vs];
    }
    __syncthreads();
    if (wave == 0) {
      const float* sp = R + lane * 84;
#pragma unroll
      for (int qs = 0; qs < 4; qs++)
#pragma unroll
        for (int vs = 0; vs < 5; vs++)
          o[qs][vs] += *(const f32x4*)(sp + (qs * 5 + vs) * 4);
    }
  }
  if (wave == 0) {
#pragma unroll
    for (int qs = 0; qs < 4; qs++) {
      float rl[4];
#pragma unroll
      for (int r = 0; r < 4; r++) {
        float lv = __shfl(o[qs][4][r], lane & 48, 64);
        rl[r] = __builtin_amdgcn_rcpf(lv);
      }
#pragma unroll
      for (int vs = 0; vs < 4; vs++)
#pragma unroll
        for (int r = 0; r < 4; r++) {
          int qrow = q0 + qs * 16 + quad * 4 + r;
          Op[(size_t)(b * 1024 + qrow) * 512 + h * 64 + vs * 16 + col] =
              f2bf(o[qs][vs][r] * rl[r]);
        }
    }
  }
}

extern "C" void kernel_launch(void* const* d_in, const int* in_sizes, int n_in,
                              void* d_out, int out_size, void* d_ws, size_t ws_size,
                              hipStream_t stream) {
  const float* q    = (const float*)d_in[0];
  const int*   mask = (const int*)d_in[1];
  const float* eps1 = (const float*)d_in[2];
  const float* U_w  = (const float*)d_in[3];
  const float* U_b  = (const float*)d_in[4];
  const float* V_w  = (const float*)d_in[5];
  const float* V_b  = (const float*)d_in[6];
  const float* ln_g = (const float*)d_in[7];
  const float* ln_b = (const float*)d_in[8];
  const float* Wq   = (const float*)d_in[9];
  const float* Wk   = (const float*)d_in[10];
  const float* Wv   = (const float*)d_in[11];
  const float* Wo   = (const float*)d_in[12];
  float* out = (float*)d_out;

  char* ws = (char*)d_ws;
  auto carve = [&](size_t bytes) { char* p = ws; ws += bytes; return p; };
  ushort* qb   = (ushort*)carve(8388608);
  ushort* uwb  = (ushort*)carve(1572864);
  ushort* vwb  = (ushort*)carve(1572864);
  ushort* e1b  = (ushort*)carve(524288);
  ushort* e1t  = (ushort*)carve(524288);
  ushort* wqkv = (ushort*)carve(1572864);
  ushort* wot  = (ushort*)carve(524288);
  ushort* A1b  = (ushort*)carve(1572864);  // A1_l = eps1 @ Uw_l.T
  ushort* Gtb  = (ushort*)carve(1572864);  // Gt_l[n][d]
  float*  cvec = (float*)carve(6144);
  unsigned long long* mbits = (unsigned long long*)carve(1048576);
  unsigned long long* mT2   = (unsigned long long*)carve(1048576);
  ushort* tb   = (ushort*)carve(8388608);
  float*  zf   = (float*)carve(16777216);
  ushort* hb   = (ushort*)carve(8388608);
  ushort* Qb   = (ushort*)carve(8388608);
  ushort* Ktt  = (ushort*)carve(8388608);
  ushort* Vtt  = (ushort*)carve(8388608);
  ushort* Ob   = (ushort*)carve(8388608);
  const int BIG = 1 << 30;

  prep_kernel<<<61824, 256, 0, stream>>>(q, mask, eps1, U_w, V_w, Wq, Wk, Wv, Wo,
                                         U_b, V_b, qb, mbits, uwb, vwb, e1b, e1t,
                                         wqkv, wot, cvec);
  mrepack_kernel<<<512, 256, 0, stream>>>(mbits, mT2);
  // A1[d, l*512+j] = sum_k eps1[d,k] Uw_l[j,k]
  gemm_nt<128><<<dim3(4, 12), 256, 0, stream>>>(
      e1b, nullptr, uwb, nullptr, BIG, 0, 512, 512,
      A1b, nullptr, A1b + 262144, nullptr, A1b + 524288, nullptr,
      nullptr, nullptr, -1, -1);
  // Gt[l*512+n, d] = sum_j Vw_l[n,j] A1_l[d,j]
  gemm_nt<64><<<dim3(12, 8), 256, 0, stream>>>(
      vwb, nullptr, A1b, nullptr, BIG, 262144, 1536, 512,
      Gtb, nullptr, nullptr, nullptr, nullptr, nullptr,
      nullptr, nullptr, -1, -1);
  const ushort* hsrc = qb;
  for (int l = 0; l < 3; l++) {
    // region0 -> t = h@eps1 (bf16), region1 -> z = h@G_l + c_l (fp32)
    gemm_nt<128><<<dim3(64, 8), 256, 0, stream>>>(
        hsrc, nullptr, e1t, Gtb + l * 262144, 512, 0, 8192, 512,
        tb, nullptr, nullptr, cvec + l * 512, nullptr, nullptr,
        nullptr, zf, -1, -1);
    ln_kernel<<<2048, 256, 0, stream>>>(zf, tb, ln_g + l * 512, ln_b + l * 512, hb);
    hsrc = hb;
  }
  // fused QKV: region0=Q (A=qb), region1=K tiled, region2=V tiled (A=hb)
  gemm_nt<128><<<dim3(64, 12), 256, 0, stream>>>(
      qb, hb, wqkv, nullptr, BIG, 0, 8192, 512,
      Qb, nullptr, Ktt, nullptr, Vtt, nullptr, nullptr, nullptr, 1, 2);
  attn_kernel<<<dim3(64, 16), 256, 0, stream>>>(Qb, Ktt, Vtt, mT2, Ob);
  gemm_nt<64><<<dim3(64, 8), 256, 0, stream>>>(
      Ob, nullptr, wot, nullptr, BIG, 0, 8192, 512,
      nullptr, nullptr, nullptr, nullptr, nullptr, nullptr, out, nullptr, -1, -1);
}

// Round 7
// 308.448 us; speedup vs baseline: 1.0421x; 1.0421x over previous
//
#include <hip/hip_runtime.h>

typedef __attribute__((ext_vector_type(8))) short bhalf8;
typedef __attribute__((ext_vector_type(4))) short bhalf4;
typedef __attribute__((ext_vector_type(4))) float f32x4;

__device__ __forceinline__ ushort f2bf(float f) {
  unsigned u = __builtin_bit_cast(unsigned, f);
  unsigned r = u + 0x7fffu + ((u >> 16) & 1u);
  return (ushort)(r >> 16);
}

// async global->LDS, 16B per lane. Dest = wave-uniform base + lane*16.
__device__ __forceinline__ void gld16(const ushort* g, ushort* l) {
  __builtin_amdgcn_global_load_lds((const __attribute__((address_space(1))) void*)g,
                                   (__attribute__((address_space(3))) void*)l, 16, 0, 0);
}

// ---------------- prep: converts, transposes, mask bitpack (inverted), cvec -
__global__ __launch_bounds__(256) void prep_kernel(
    const float* __restrict__ q, const int* __restrict__ mask,
    const float* __restrict__ eps1, const float* __restrict__ U_w,
    const float* __restrict__ V_w, const float* __restrict__ Wq,
    const float* __restrict__ Wk, const float* __restrict__ Wv,
    const float* __restrict__ Wo, const float* __restrict__ U_b,
    const float* __restrict__ V_b,
    ushort* __restrict__ qb, unsigned long long* __restrict__ minv,
    ushort* __restrict__ uwb, ushort* __restrict__ vwb,
    ushort* __restrict__ e1b, ushort* __restrict__ e1t,
    ushort* __restrict__ wqkv, ushort* __restrict__ wot,
    float* __restrict__ cvec) {
  int i = blockIdx.x * 256 + threadIdx.x;
  if (i < 4194304) {
    qb[i] = f2bf(q[i]);
  } else if (i < 12582912) {
    int j = i - 4194304;  // (b,qq,g) flat
    unsigned long long bb = __ballot(mask[j] != 0);
    if ((threadIdx.x & 63) == 0) {
      int b = j >> 20, qq = (j >> 10) & 1023, g = j & 1023;
      // minv[b][g>>6][q]: bit (g&63) == 1 means KEEP (mask==0)
      minv[((size_t)b * 16 + (g >> 6)) * 1024 + qq] = ~bb;
    }
  } else if (i < 13369344) {
    int j = i - 12582912;
    uwb[j] = f2bf(U_w[j]);
  } else if (i < 14155776) {
    int j = i - 13369344;
    vwb[j] = f2bf(V_w[j]);
  } else if (i < 14417920) {
    int j = i - 14155776;
    e1b[j] = f2bf(eps1[j]);
  } else if (i < 14680064) {
    int j = i - 14417920; int n = j >> 9, k = j & 511;
    e1t[j] = f2bf(eps1[k * 512 + n]);
  } else if (i < 15466496) {
    int j = i - 14680064; int n = j >> 9, d = j & 511;
    const float* W = (n < 512) ? Wq : (n < 1024 ? Wk : Wv);
    float sc = (n < 512) ? 0.02255252509f : 1.0f;  // (1/64)*log2(e) into Wq
    int nl = n & 511;
    wqkv[j] = f2bf(W[((nl >> 6) * 512 + d) * 64 + (nl & 63)] * sc);
  } else if (i < 15728640) {
    int j = i - 15466496; int d = j >> 9, hv = j & 511;
    wot[j] = f2bf(Wo[hv * 512 + d]);
  } else {
    int j = i - 15728640;  // cvec: 98304 threads = 1536 waves
    int idx = j >> 6, ln = j & 63;
    int l = idx >> 9;
    const float* vr = V_w + (size_t)idx * 512 + ln * 8;
    const float* ur = U_b + l * 512 + ln * 8;
    float s = 0;
#pragma unroll
    for (int t = 0; t < 8; t++) s += vr[t] * ur[t];
#pragma unroll
    for (int off = 1; off < 64; off <<= 1) s += __shfl_xor(s, off, 64);
    if (ln == 0) cvec[idx] = s + V_b[idx];
  }
}

// ---------------- bf16 MFMA GEMM, NT, BK=32, pipelined gld16 ----------------
// C[M,N]=A[M,K]*Bt[N,K]^T, tile 128 x BN, 256 thr, grid(x=m-blocks,y=n-blocks)
// (same-x blocks share an XCD -> A L2 reuse). Output region reg=n0>>9 with
// per-region code: 0=bf16 row-major, 1=fp32 row-major (ptr cast), 2=MFMA-tile
// scatter T[bh][t/16][d/32][t%16][d%32], 3=V^T tile scatter T[bh][g/16][v][g%16].
template <int BN>
__global__ __launch_bounds__(256) void gemm_nt(
    const ushort* __restrict__ A0, const ushort* __restrict__ A1,
    const ushort* __restrict__ Bt0, const ushort* __restrict__ Bt1,
    int bsplit, int mstride, int M, int K,
    ushort* __restrict__ Oa, const float* __restrict__ ba, int ca,
    ushort* __restrict__ Ob, const float* __restrict__ bb2, int cb,
    ushort* __restrict__ Oc, const float* __restrict__ bc, int cc) {
  __shared__ ushort As[128 * 32];
  __shared__ ushort Bs[BN * 32];
  int tid = threadIdx.x;
  int wave = tid >> 6, lane = tid & 63;
  int quad = lane >> 4, col = lane & 15;
  int m0 = blockIdx.x * 128, n0 = blockIdx.y * BN;
  const ushort* A = (A1 && n0 >= 512) ? A1 : A0;
  const ushort* Bp = ((n0 < bsplit) ? Bt0 + (size_t)n0 * K
                                    : Bt1 + (size_t)(n0 - bsplit) * K) +
                     (size_t)(m0 >> 9) * mstride;
  constexpr int NI = BN / 32;
  int wm = (BN == 128) ? (wave >> 1) * 64 : (wave & 1) * 64;
  int wn = (BN == 128) ? (wave & 1) * 64 : (wave >> 1) * 32;
  f32x4 acc[4][NI] = {};
  int srow = wave * 16 + (lane >> 2);
  int skc = (lane & 3) * 8;
  const ushort* gA0 = A + (size_t)(m0 + srow) * K + skc;
  const ushort* gA1 = gA0 + (size_t)64 * K;
  const ushort* gB0 = Bp + (size_t)srow * K + skc;
  const ushort* gB1 = gB0 + (size_t)64 * K;
  ushort* lA0 = &As[wave * 16 * 32];
  ushort* lA1 = &As[(64 + wave * 16) * 32];
  ushort* lB0 = &Bs[wave * 16 * 32];
  ushort* lB1 = (BN == 128) ? &Bs[(64 + wave * 16) * 32] : nullptr;

  gld16(gA0, lA0);
  gld16(gA1, lA1);
  gld16(gB0, lB0);
  if (BN == 128) gld16(gB1, lB1);

  for (int k0 = 0; k0 < K; k0 += 32) {
    __syncthreads();  // vmcnt drained: tile staged; prev readers done
    bhalf8 af[4], bg[NI];
#pragma unroll
    for (int i = 0; i < 4; i++)
      af[i] = *(bhalf8*)&As[(wm + i * 16 + col) * 32 + quad * 8];
#pragma unroll
    for (int i = 0; i < NI; i++)
      bg[i] = *(bhalf8*)&Bs[(wn + i * 16 + col) * 32 + quad * 8];
    __syncthreads();  // frags in regs; LDS free to overwrite
    if (k0 + 32 < K) {  // stage next tile; DMA overlaps MFMA below
      gld16(gA0 + k0 + 32, lA0);
      gld16(gA1 + k0 + 32, lA1);
      gld16(gB0 + k0 + 32, lB0);
      if (BN == 128) gld16(gB1 + k0 + 32, lB1);
    }
#pragma unroll
    for (int mi = 0; mi < 4; mi++)
#pragma unroll
      for (int ni = 0; ni < NI; ni++)
        acc[mi][ni] = __builtin_amdgcn_mfma_f32_16x16x32_bf16(af[mi], bg[ni], acc[mi][ni], 0, 0, 0);
  }

  int reg = n0 >> 9;
  ushort* O = (reg == 0) ? Oa : (reg == 1 ? Ob : Oc);
  const float* bs = (reg == 0) ? ba : (reg == 1 ? bb2 : bc);
  int code = (reg == 0) ? ca : (reg == 1 ? cb : cc);
#pragma unroll
  for (int mi = 0; mi < 4; mi++)
#pragma unroll
    for (int ni = 0; ni < NI; ni++) {
      int cn = n0 + wn + ni * 16 + col;
      int cnl = cn & 511;
      int cmb = m0 + wm + mi * 16 + quad * 4;
      float bv = bs ? bs[cnl] : 0.f;
      if (code == 2) {
        int bhh = (cmb >> 10) * 8 + (cnl >> 6);
        size_t base = ((size_t)bhh * 64 + ((cmb & 1023) >> 4)) * 1024 +
                      (size_t)((cnl >> 5) & 1) * 512 + (size_t)(cmb & 15) * 32 + (cnl & 31);
#pragma unroll
        for (int r = 0; r < 4; r++)
          O[base + r * 32] = f2bf(acc[mi][ni][r] + bv);
      } else if (code == 3) {
        int bhh = (cmb >> 10) * 8 + (cnl >> 6);
        size_t base = ((size_t)bhh * 64 + ((cmb & 1023) >> 4)) * 1024 +
                      (size_t)(cnl & 63) * 16 + (cmb & 15);
        ushort4 pk;
        pk.x = f2bf(acc[mi][ni][0] + bv);
        pk.y = f2bf(acc[mi][ni][1] + bv);
        pk.z = f2bf(acc[mi][ni][2] + bv);
        pk.w = f2bf(acc[mi][ni][3] + bv);
        *(ushort4*)&O[base] = pk;
      } else if (code == 1) {
        float* Ff = (float*)O;
#pragma unroll
        for (int r = 0; r < 4; r++)
          Ff[(size_t)(cmb + r) * 512 + cnl] = acc[mi][ni][r] + bv;
      } else {
#pragma unroll
        for (int r = 0; r < 4; r++)
          O[(size_t)(cmb + r) * 512 + cnl] = f2bf(acc[mi][ni][r] + bv);
      }
    }
}

// ---------------- fused LayerNorm + ReLU + residual (z fp32, t bf16) --------
__global__ __launch_bounds__(256) void ln_kernel(
    const float* __restrict__ z, const ushort* __restrict__ tb,
    const float* __restrict__ lgam, const float* __restrict__ lbet,
    ushort* __restrict__ hb) {
  int row = blockIdx.x * 4 + (threadIdx.x >> 6);
  int lane = threadIdx.x & 63;
  int cbase = lane * 8;
  const float* zr = z + (size_t)row * 512 + cbase;
  float x[8];
  *(float4*)&x[0] = *(const float4*)zr;
  *(float4*)&x[4] = *(const float4*)(zr + 4);
  float sum = 0;
#pragma unroll
  for (int i = 0; i < 8; i++) sum += x[i];
#pragma unroll
  for (int off = 1; off < 64; off <<= 1) sum += __shfl_xor(sum, off, 64);
  float mu = sum * (1.f / 512.f);
  float vs = 0;
#pragma unroll
  for (int i = 0; i < 8; i++) { float d = x[i] - mu; vs += d * d; }
#pragma unroll
  for (int off = 1; off < 64; off <<= 1) vs += __shfl_xor(vs, off, 64);
  float rstd = rsqrtf(vs * (1.f / 512.f) + 1e-5f);
  uint4 tr = *(const uint4*)&tb[(size_t)row * 512 + cbase];
  float tv[8];
  {
    const unsigned* u = (const unsigned*)&tr;
#pragma unroll
    for (int w = 0; w < 4; w++) {
      tv[2 * w] = __builtin_bit_cast(float, u[w] << 16);
      tv[2 * w + 1] = __builtin_bit_cast(float, u[w] & 0xFFFF0000u);
    }
  }
  ushort outv[8];
#pragma unroll
  for (int i = 0; i < 8; i++) {
    float val = (x[i] - mu) * rstd * lgam[cbase + i] + lbet[cbase + i];
    outv[i] = f2bf(tv[i] + fmaxf(val, 0.f));
  }
  *(uint4*)&hb[(size_t)row * 512 + cbase] = *(uint4*)outv;
}

// ---------------- flash attention, operand-swapped, all-register loop -------
// grid (64 bh, 16 qt). Computes S^T = K*Q^T so S^T's C-layout (g=quad*4+r,
// q=col) IS the B-layout of mfma_16x16x16bf16_1k (k=quad*4+j): exp'd P packs
// straight into PV B-fragments in registers. PV: O^T[v][q] += V^T * P, K=16.
// No LDS in the main loop; lsum per lane (all its P share q=col per qtile).
// Wave w owns g-slab g0+w*32. Q/K tiled [bh][t/16][d/32][t%16][d%32],
// V^T tiled [bh][g/16][v][g%16], mask minv[b][g>>6][q] pre-inverted.
__global__ __launch_bounds__(256, 3) void attn_kernel(
    const ushort* __restrict__ QtT, const ushort* __restrict__ KtT,
    const ushort* __restrict__ VtT, const unsigned long long* __restrict__ minv,
    ushort* __restrict__ Op) {
  int bh = blockIdx.x, qt0 = blockIdx.y;
  int b = bh >> 3, h = bh & 7;
  __shared__ float R[64 * 68];
  int tid = threadIdx.x, w = tid >> 6, lane = tid & 63;
  int quad = lane >> 4, col = lane & 15;
  int q0 = qt0 * 64;
  const ushort* Kt = KtT + (size_t)bh * 65536 + col * 32 + quad * 8;
  const ushort* Vt = VtT + (size_t)bh * 65536 + col * 16 + quad * 4;
  const ushort* Qt = QtT + (size_t)bh * 65536 + col * 32 + quad * 8;
  bhalf8 bq[4][2];
#pragma unroll
  for (int qt = 0; qt < 4; qt++)
#pragma unroll
    for (int ks = 0; ks < 2; ks++)
      bq[qt][ks] = *(const bhalf8*)(Qt + (size_t)(qt0 * 4 + qt) * 1024 + ks * 512);
  f32x4 o[4][4] = {};  // [vt][qt], O^T C-layout: v=vt*16+quad*4+r, q=qt*16+col
  float lsum[4] = {0.f, 0.f, 0.f, 0.f};
  const unsigned long long* mb = minv + (size_t)b * 16384 + q0 + col;

  for (int g0 = 0; g0 < 1024; g0 += 128) {
    int gs = g0 + w * 32;
    int gw = gs >> 6;
    int sb = (gs & 32) + quad * 4;
    unsigned shq[4];
#pragma unroll
    for (int qt = 0; qt < 4; qt++)
      shq[qt] = (unsigned)(mb[gw * 1024 + qt * 16] >> sb);
#pragma unroll
    for (int gt = 0; gt < 2; gt++) {
      size_t gblk = (size_t)((gs >> 4) + gt) * 1024;
      bhalf8 ak0 = *(const bhalf8*)(Kt + gblk);
      bhalf8 ak1 = *(const bhalf8*)(Kt + gblk + 512);
      bhalf4 av[4];
#pragma unroll
      for (int vt = 0; vt < 4; vt++)
        av[vt] = *(const bhalf4*)(Vt + gblk + vt * 256);
#pragma unroll
      for (int qt = 0; qt < 4; qt++) {
        f32x4 s = {};
        s = __builtin_amdgcn_mfma_f32_16x16x32_bf16(ak0, bq[qt][0], s, 0, 0, 0);
        s = __builtin_amdgcn_mfma_f32_16x16x32_bf16(ak1, bq[qt][1], s, 0, 0, 0);
        unsigned sh = shq[qt];
        unsigned pu[4];
#pragma unroll
        for (int r = 0; r < 4; r++) {
          const int pos = gt * 16 + r;  // compile-time
          unsigned keep = (unsigned)((int)(sh << (31 - pos)) >> 31);
          pu[r] = __builtin_bit_cast(unsigned, __builtin_amdgcn_exp2f(s[r])) & keep;
          lsum[qt] += __builtin_bit_cast(float, pu[r]);
        }
        uint2 pp;
        pp.x = ((pu[0] + 0x8000u) >> 16) | (((pu[1] + 0x8000u) >> 16) << 16);
        pp.y = ((pu[2] + 0x8000u) >> 16) | (((pu[3] + 0x8000u) >> 16) << 16);
        bhalf4 bp = __builtin_bit_cast(bhalf4, pp);
#pragma unroll
        for (int vt = 0; vt < 4; vt++)
          o[vt][qt] = __builtin_amdgcn_mfma_f32_16x16x16bf16_1k(av[vt], bp, o[vt][qt], 0, 0, 0);
      }
    }
  }
  // cross-wave reduce (partial O over g-slabs) + lsum
  for (int src = 1; src < 4; src++) {
    __syncthreads();
    if (w == src) {
      float* dst = R + lane * 68;
#pragma unroll
      for (int vt = 0; vt < 4; vt++)
#pragma unroll
        for (int qt = 0; qt < 4; qt++)
          *(f32x4*)(dst + (vt * 4 + qt) * 4) = o[vt][qt];
#pragma unroll
      for (int qt = 0; qt < 4; qt++) dst[64 + qt] = lsum[qt];
    }
    __syncthreads();
    if (w == 0) {
      const float* sp = R + lane * 68;
#pragma unroll
      for (int vt = 0; vt < 4; vt++)
#pragma unroll
        for (int qt = 0; qt < 4; qt++)
          o[vt][qt] += *(const f32x4*)(sp + (vt * 4 + qt) * 4);
#pragma unroll
      for (int qt = 0; qt < 4; qt++) lsum[qt] += sp[64 + qt];
    }
  }
  if (w == 0) {
    float rl[4];
#pragma unroll
    for (int qt = 0; qt < 4; qt++) {
      lsum[qt] += __shfl_xor(lsum[qt], 16, 64);
      lsum[qt] += __shfl_xor(lsum[qt], 32, 64);
      rl[qt] = __builtin_amdgcn_rcpf(lsum[qt]);
    }
#pragma unroll
    for (int vt = 0; vt < 4; vt++)
#pragma unroll
      for (int qt = 0; qt < 4; qt++) {
        ushort4 pk;
        pk.x = f2bf(o[vt][qt][0] * rl[qt]);
        pk.y = f2bf(o[vt][qt][1] * rl[qt]);
        pk.z = f2bf(o[vt][qt][2] * rl[qt]);
        pk.w = f2bf(o[vt][qt][3] * rl[qt]);
        *(ushort4*)&Op[(size_t)(b * 1024 + q0 + qt * 16 + col) * 512 +
                       h * 64 + vt * 16 + quad * 4] = pk;
      }
  }
}

extern "C" void kernel_launch(void* const* d_in, const int* in_sizes, int n_in,
                              void* d_out, int out_size, void* d_ws, size_t ws_size,
                              hipStream_t stream) {
  const float* q    = (const float*)d_in[0];
  const int*   mask = (const int*)d_in[1];
  const float* eps1 = (const float*)d_in[2];
  const float* U_w  = (const float*)d_in[3];
  const float* U_b  = (const float*)d_in[4];
  const float* V_w  = (const float*)d_in[5];
  const float* V_b  = (const float*)d_in[6];
  const float* ln_g = (const float*)d_in[7];
  const float* ln_b = (const float*)d_in[8];
  const float* Wq   = (const float*)d_in[9];
  const float* Wk   = (const float*)d_in[10];
  const float* Wv   = (const float*)d_in[11];
  const float* Wo   = (const float*)d_in[12];
  float* out = (float*)d_out;

  char* ws = (char*)d_ws;
  auto carve = [&](size_t bytes) { char* p = ws; ws += bytes; return p; };
  ushort* qb   = (ushort*)carve(8388608);
  ushort* uwb  = (ushort*)carve(1572864);
  ushort* vwb  = (ushort*)carve(1572864);
  ushort* e1b  = (ushort*)carve(524288);
  ushort* e1t  = (ushort*)carve(524288);
  ushort* wqkv = (ushort*)carve(1572864);
  ushort* wot  = (ushort*)carve(524288);
  ushort* A1b  = (ushort*)carve(1572864);  // A1_l = eps1 @ Uw_l.T
  ushort* Gtb  = (ushort*)carve(1572864);  // Gt_l[n][d]
  float*  cvec = (float*)carve(6144);
  unsigned long long* minv = (unsigned long long*)carve(1048576);
  ushort* tb   = (ushort*)carve(8388608);
  float*  zf   = (float*)carve(16777216);
  ushort* hb   = (ushort*)carve(8388608);
  ushort* Qtt  = (ushort*)carve(8388608);
  ushort* Ktt  = (ushort*)carve(8388608);
  ushort* Vtt  = (ushort*)carve(8388608);
  ushort* Ob   = (ushort*)carve(8388608);
  const int BIG = 1 << 30;

  prep_kernel<<<61824, 256, 0, stream>>>(q, mask, eps1, U_w, V_w, Wq, Wk, Wv, Wo,
                                         U_b, V_b, qb, minv, uwb, vwb, e1b, e1t,
                                         wqkv, wot, cvec);
  // A1[d, l*512+j] = sum_k eps1[d,k] Uw_l[j,k]
  gemm_nt<128><<<dim3(4, 12), 256, 0, stream>>>(
      e1b, nullptr, uwb, nullptr, BIG, 0, 512, 512,
      A1b, nullptr, 0, A1b + 262144, nullptr, 0, A1b + 524288, nullptr, 0);
  // Gt[l*512+n, d] = sum_j Vw_l[n,j] A1_l[d,j]
  gemm_nt<64><<<dim3(12, 8), 256, 0, stream>>>(
      vwb, nullptr, A1b, nullptr, BIG, 262144, 1536, 512,
      Gtb, nullptr, 0, nullptr, nullptr, 0, nullptr, nullptr, 0);
  const ushort* hsrc = qb;
  for (int l = 0; l < 3; l++) {
    // region0 -> t = h@eps1 (bf16), region1 -> z = h@G_l + c_l (fp32)
    gemm_nt<128><<<dim3(64, 8), 256, 0, stream>>>(
        hsrc, nullptr, e1t, Gtb + l * 262144, 512, 0, 8192, 512,
        tb, nullptr, 0, (ushort*)zf, cvec + l * 512, 1, nullptr, nullptr, 0);
    ln_kernel<<<2048, 256, 0, stream>>>(zf, tb, ln_g + l * 512, ln_b + l * 512, hb);
    hsrc = hb;
  }
  // fused QKV: region0=Q tiled (A=qb), region1=K tiled, region2=V^T tiled (A=hb)
  gemm_nt<128><<<dim3(64, 12), 256, 0, stream>>>(
      qb, hb, wqkv, nullptr, BIG, 0, 8192, 512,
      Qtt, nullptr, 2, Ktt, nullptr, 2, Vtt, nullptr, 3);
  attn_kernel<<<dim3(64, 16), 256, 0, stream>>>(Qtt, Ktt, Vtt, minv, Ob);
  gemm_nt<64><<<dim3(64, 8), 256, 0, stream>>>(
      Ob, nullptr, wot, nullptr, BIG, 0, 8192, 512,
      (ushort*)out, nullptr, 1, nullptr, nullptr, 0, nullptr, nullptr, 0);
}